// Round 8
// baseline (1549.502 us; speedup 1.0000x reference)
//
#include <hip/hip_runtime.h>

// LSTM BS=512, T=2048, IN=64, HS=128.  Single fused persistent kernel.
// 256 blocks x 2 batch rows, 8 waves. Scan body = R5's (best measured):
// Z read at step top, n-outer MFMA chains order {i,g,f,o}, setprio.
// Z production: CH=32 double-buffered LDS; one 16-row m-tile of chunk c+1
// produced per 8 scan steps, SPLIT into front (cvt+MFMA issue+x-load issue,
// placed after scan MFMAs -> fills idle matrix pipe; x-loads get 8 steps of
// latency cover) and back (pack+ds_write, placed after the h-write so no
// critical-path DS op queues behind it).

#define T_STEPS 2048
#define IN_DIM 64
#define HS 128
#define NG 512
#define ROWS 2
#define NBLK 256
#define NTHR 512
#define HSTR 144
#define CH 32
#define NCH (T_STEPS / CH)

typedef float f32x4 __attribute__((ext_vector_type(4)));
typedef short s16x8 __attribute__((ext_vector_type(8)));

__device__ __forceinline__ unsigned short f2bf(float f) {
  unsigned u = __float_as_uint(f);
  return (unsigned short)((u + 0x7fffu + ((u >> 16) & 1u)) >> 16);  // RNE
}
__device__ __forceinline__ float bf2f(unsigned short s) {
  return __int_as_float(((int)s) << 16);
}
__device__ __forceinline__ float rcpf(float x) { return __builtin_amdgcn_rcpf(x); }
__device__ __forceinline__ float sigm(float x) { return rcpf(1.0f + __expf(-x)); }
__device__ __forceinline__ float tanhfast(float x) {
  return 1.0f - 2.0f * rcpf(__expf(2.0f * x) + 1.0f);  // exact at +-inf
}

__global__ __launch_bounds__(NTHR, 1)
void lstm_fused(const float* __restrict__ X, const float* __restrict__ W,
                const float* __restrict__ U, const float* __restrict__ B,
                const float* __restrict__ LW, const float* __restrict__ LB,
                float* __restrict__ OUT) {
  // Zc[buf] cell (tl, col): 8 shorts = [r0:n0..n3 | r1:n0..n3]
  __shared__ __align__(16) short Zc[2][CH * 128 * 8];  // 2 x 64 KB
  __shared__ __align__(16) short Hb[2][ROWS * HSTR];   // h double buffer
  __shared__ float Ys[256];
  __shared__ float Ps[8];

  const int tid  = threadIdx.x;
  const int lane = tid & 63;
  const int w    = tid >> 6;
  const int blk  = blockIdx.x;
  const int lrow = lane & 15;
  const int lg   = lane >> 4;
  const int col8 = (w * 16 + lrow) * 8;   // Zc column offset (shorts)

  // ---- persistent weight fragments: wave w owns col p = n*128 + 16w + lrow
  s16x8 bfrU[4][4];   // K=128 (U)
  s16x8 bfrW[4][2];   // K=64  (W)
  float biasg[4];
#pragma unroll
  for (int n = 0; n < 4; ++n) {
    const int p = n * HS + w * 16 + lrow;
#pragma unroll
    for (int kt = 0; kt < 4; ++kt)
#pragma unroll
      for (int j = 0; j < 8; ++j)
        bfrU[n][kt][j] = (short)f2bf(U[(kt * 32 + (lg << 3) + j) * NG + p]);
#pragma unroll
    for (int kt = 0; kt < 2; ++kt)
#pragma unroll
      for (int j = 0; j < 8; ++j)
        bfrW[n][kt][j] = (short)f2bf(W[(kt * 32 + (lg << 3) + j) * NG + p]);
    biasg[n] = B[p];
  }

  // ---- GEMM A-tile source: lane -> batch row (lrow&1), t-row (lrow>>1) ----
  const float* xbA = X + ((long)(blk * ROWS + (lrow & 1)) * T_STEPS + (lrow >> 1)) * IN_DIM + (lg << 3);

  // q regs: x for the NEXT m-tile to be produced (chunk 0, mt 0 initially)
  f32x4 q0 = *(const f32x4*)(xbA);
  f32x4 q1 = *(const f32x4*)(xbA + 4);
  f32x4 q2 = *(const f32x4*)(xbA + 32);
  f32x4 q3 = *(const f32x4*)(xbA + 36);

  f32x4 gac[4];   // gemm accumulators, live between front and back halves

  // front: cvt q -> A frags, init+issue 8 MFMAs into gac, issue next x loads
  auto gemm_front = [&](long noff) {
    s16x8 a0, a1;
#pragma unroll
    for (int j = 0; j < 4; ++j) {
      a0[j] = (short)f2bf(q0[j]); a0[4 + j] = (short)f2bf(q1[j]);
      a1[j] = (short)f2bf(q2[j]); a1[4 + j] = (short)f2bf(q3[j]);
    }
    const float* pn = xbA + noff;
    const f32x4 t0 = *(const f32x4*)(pn);
    const f32x4 t1 = *(const f32x4*)(pn + 4);
    const f32x4 t2 = *(const f32x4*)(pn + 32);
    const f32x4 t3 = *(const f32x4*)(pn + 36);
#pragma unroll
    for (int n = 0; n < 4; ++n) {
      gac[n][0] = biasg[n]; gac[n][1] = biasg[n];
      gac[n][2] = biasg[n]; gac[n][3] = biasg[n];
    }
#pragma unroll
    for (int n = 0; n < 4; ++n)
      gac[n] = __builtin_amdgcn_mfma_f32_16x16x32_bf16(a0, bfrW[n][0], gac[n], 0, 0, 0);
#pragma unroll
    for (int n = 0; n < 4; ++n)
      gac[n] = __builtin_amdgcn_mfma_f32_16x16x32_bf16(a1, bfrW[n][1], gac[n], 0, 0, 0);
    q0 = t0; q1 = t1; q2 = t2; q3 = t3;
  };
  // back: pack gac -> bf16 chunk cells, store to Zc[nbuf]
  auto gemm_back = [&](int mt, int nbuf) {
    // D row d=4lg+rr -> m-row 16mt+d -> (tl = 8mt+2lg+(rr>>1), r = rr&1)
    s16x8 z0, z1;
#pragma unroll
    for (int n = 0; n < 4; ++n) {
      z0[n] = (short)f2bf(gac[n][0]); z0[4 + n] = (short)f2bf(gac[n][1]);
      z1[n] = (short)f2bf(gac[n][2]); z1[4 + n] = (short)f2bf(gac[n][3]);
    }
    const int tl0 = mt * 8 + 2 * lg;
    *(s16x8*)&Zc[nbuf][tl0 * 1024 + col8]       = z0;
    *(s16x8*)&Zc[nbuf][(tl0 + 1) * 1024 + col8] = z1;
  };

  // ---- prologue: produce chunk 0 into Zc[0] (dedicated) ----
#pragma unroll
  for (int mt = 0; mt < 4; ++mt) {
    const long noff = (mt < 3) ? (long)(mt + 1) * 8 * IN_DIM
                               : (long)CH * IN_DIM;   // chunk 1, mt 0
    gemm_front(noff);
    gemm_back(mt, 0);
  }

  s16x8 afr[4];
  const s16x8 zer = {0, 0, 0, 0, 0, 0, 0, 0};
#pragma unroll
  for (int kt = 0; kt < 4; ++kt) afr[kt] = zer;  // h(0) = 0

  float creg = 0.f, hreg = 0.f;
  __syncthreads();

#pragma unroll 1
  for (int c = 0; c < NCH; ++c) {
    const int cur = c & 1;
#pragma unroll 1
    for (int tl = 0; tl < CH; ++tl) {
      const int t = c * CH + tl;
      const bool do_gemm = ((tl & 7) == 4) && (c + 1 < NCH);
      const int  mt = tl >> 3;

      // Z for this step (broadcast ds_read, R5 placement)
      const s16x8 zc = *(const s16x8*)&Zc[cur][tl * 1024 + col8];
      f32x4 acc[4];
#pragma unroll
      for (int n = 0; n < 4; ++n) {
        acc[n][0] = bf2f((unsigned short)zc[n]);
        acc[n][1] = bf2f((unsigned short)zc[4 + n]);
        acc[n][2] = 0.f; acc[n][3] = 0.f;
      }

      // n-outer chains, order {0,2,1,3} (i,g retire first) -- R5 body
      __builtin_amdgcn_s_setprio(1);
#pragma unroll
      for (int kt = 0; kt < 4; ++kt)
        acc[0] = __builtin_amdgcn_mfma_f32_16x16x32_bf16(afr[kt], bfrU[0][kt], acc[0], 0, 0, 0);
#pragma unroll
      for (int kt = 0; kt < 4; ++kt)
        acc[2] = __builtin_amdgcn_mfma_f32_16x16x32_bf16(afr[kt], bfrU[2][kt], acc[2], 0, 0, 0);
#pragma unroll
      for (int kt = 0; kt < 4; ++kt)
        acc[1] = __builtin_amdgcn_mfma_f32_16x16x32_bf16(afr[kt], bfrU[1][kt], acc[1], 0, 0, 0);
#pragma unroll
      for (int kt = 0; kt < 4; ++kt)
        acc[3] = __builtin_amdgcn_mfma_f32_16x16x32_bf16(afr[kt], bfrU[3][kt], acc[3], 0, 0, 0);
      __builtin_amdgcn_s_setprio(0);

      // producer front half: MFMAs queue behind the scan chains (idle pipe),
      // x-loads for the NEXT m-tile get ~8 steps of latency cover.
      if (do_gemm) {
        long noff;
        if (mt < 3) noff = (long)(c + 1) * CH * IN_DIM + (long)(mt + 1) * 8 * IN_DIM;
        else        noff = (long)((c + 2 < NCH) ? c + 2 : c + 1) * CH * IN_DIM;
        gemm_front(noff);
      }

      // i,g first (their accs finish first), f,o while i*g computes
      const float s0 = __int_as_float(
          __builtin_amdgcn_ds_swizzle(__float_as_int(acc[0][1]), 0x401F));
      const float s2 = __int_as_float(
          __builtin_amdgcn_ds_swizzle(__float_as_int(acc[2][1]), 0x401F));
      const float v0 = (lane & 16) ? s0 : acc[0][0];
      const float v2 = (lane & 16) ? s2 : acc[2][0];
      const float iv = sigm(v0), gv = tanhfast(v2);
      const float pg = iv * gv;
      const float s1 = __int_as_float(
          __builtin_amdgcn_ds_swizzle(__float_as_int(acc[1][1]), 0x401F));
      const float s3 = __int_as_float(
          __builtin_amdgcn_ds_swizzle(__float_as_int(acc[3][1]), 0x401F));
      const float v1 = (lane & 16) ? s1 : acc[1][0];
      const float v3 = (lane & 16) ? s3 : acc[3][0];
      const float fv = sigm(v1), ov = sigm(v3);
      creg = fv * creg + pg;
      hreg = ov * tanhfast(creg);

      if (lane < 32) {
        const int col = w * 16 + lrow;
        const int r   = lg & 1;
        if (t < T_STEPS - 1) {
          Hb[(t + 1) & 1][r * HSTR + col] = (short)f2bf(hreg);
        } else {
          const int row = blk * ROWS + r;
          OUT[512 + row * HS + col]   = hreg;   // h_t
          OUT[66048 + row * HS + col] = creg;   // c_t
          Ys[r * HS + col] = LW[col] * hreg;    // y partials
        }
      }

      // producer back half: after all critical-path DS ops of this step;
      // gemm MFMA results retired long ago, so the barrier isn't extended.
      if (do_gemm) gemm_back(mt, cur ^ 1);

      __syncthreads();

      if (t < T_STEPS - 1 && lrow < ROWS) {     // h fragments for step t+1
        const short* hb = &Hb[(t + 1) & 1][lrow * HSTR];
        afr[0] = *(const s16x8*)&hb[(lg << 3)];
        afr[1] = *(const s16x8*)&hb[32 + (lg << 3)];
        afr[2] = *(const s16x8*)&hb[64 + (lg << 3)];
        afr[3] = *(const s16x8*)&hb[96 + (lg << 3)];
      }
    }
  }

  // ---- y = h @ linear_w.T + b ----
  if (tid < 8) {
    const int r = tid >> 2, seg = tid & 3;
    float s = 0.f;
#pragma unroll 8
    for (int j = 0; j < 32; ++j) s += Ys[r * 128 + seg * 32 + j];
    Ps[tid] = s;
  }
  __syncthreads();
  if (tid < ROWS) {
    OUT[blk * ROWS + tid] = LB[0] + Ps[tid * 4] + Ps[tid * 4 + 1]
                                  + Ps[tid * 4 + 2] + Ps[tid * 4 + 3];
  }
}

extern "C" void kernel_launch(void* const* d_in, const int* in_sizes, int n_in,
                              void* d_out, int out_size, void* d_ws, size_t ws_size,
                              hipStream_t stream) {
  const float* X  = (const float*)d_in[0];
  const float* W  = (const float*)d_in[1];
  const float* U  = (const float*)d_in[2];
  const float* B  = (const float*)d_in[3];
  const float* LW = (const float*)d_in[4];
  const float* LB = (const float*)d_in[5];
  lstm_fused<<<dim3(NBLK), dim3(NTHR), 0, stream>>>(X, W, U, B, LW, LB, (float*)d_out);
}

// Round 9
// 1370.567 us; speedup vs baseline: 1.1306x; 1.1306x over previous
//
#include <hip/hip_runtime.h>

// LSTM BS=512, T=2048, IN=64, HS=128.
// One dispatch, 256 blocks x 512 thr:
//   blocks 0..31   (scan):     16 batch rows each -> A-tile fully dense.
//     Per step: 16 MFMA/wave (K=128 U*h, zero M-padding), acc C-init from
//     global Z (2-step reg prefetch), 4 full in-register cell updates per
//     lane (no swizzle: lane holds i,f,g,o at 4 (row,col) pairs).
//   blocks 32..255 (producer): Z = x@W + bias for (group g, 32-step chunk c)
//     units in c-major order, written to d_ws in scan-native per-lane layout,
//     published via device-scope release flags; scan acquires per chunk.
// All 256 blocks co-resident (1/CU) -> producer/consumer spin is safe.

#define T_STEPS 2048
#define IN_DIM 64
#define HS 128
#define NG 512
#define NTHR 512
#define HSTR 136
#define CHK 32
#define NCHK 64
#define GROUPS 32
#define RPG 16
#define PRODS 224
#define NUNITS (NCHK * GROUPS)

typedef float f32x4 __attribute__((ext_vector_type(4)));
typedef short s16x8 __attribute__((ext_vector_type(8)));

__device__ __forceinline__ unsigned short f2bf(float f) {
  unsigned u = __float_as_uint(f);
  return (unsigned short)((u + 0x7fffu + ((u >> 16) & 1u)) >> 16);  // RNE
}
__device__ __forceinline__ float bf2f(unsigned short s) {
  return __int_as_float(((int)s) << 16);
}
__device__ __forceinline__ float rcpf(float x) { return __builtin_amdgcn_rcpf(x); }
__device__ __forceinline__ float sigm(float x) { return rcpf(1.0f + __expf(-x)); }
__device__ __forceinline__ float tanhfast(float x) {
  return 1.0f - 2.0f * rcpf(__expf(2.0f * x) + 1.0f);  // exact at +-inf
}

__device__ __forceinline__ void wait_flag(int* f) {
  int tries = 0;
  while (__hip_atomic_load(f, __ATOMIC_ACQUIRE, __HIP_MEMORY_SCOPE_AGENT) == 0) {
    __builtin_amdgcn_s_sleep(32);
    if (++tries > (1 << 24)) break;   // safety bound; never hit in practice
  }
}

// ---------------------------------------------------------------------------
// Fused producer/consumer kernel.
// Z element layout: chunk16 = Zbuf[((t*32 + g)*512 + tid)*16 .. +16) shorts,
//   shorts[r*4 + n] = gate n, row 16g+4*(tid>>4 &3)... = (4*lg+r), col 16w+lrow.
// ---------------------------------------------------------------------------
__global__ __launch_bounds__(NTHR, 1)
void lstm_mega(const float* __restrict__ X, const float* __restrict__ W,
               const float* __restrict__ U, const float* __restrict__ B,
               const float* __restrict__ LW, const float* __restrict__ LB,
               float* __restrict__ OUT, unsigned short* __restrict__ Zbuf,
               int* __restrict__ flags) {
  __shared__ __align__(16) short Hb[2][RPG * HSTR];   // h double buffer (bf16)
  __shared__ float Ys[RPG * HS];

  const int tid  = threadIdx.x;
  const int lane = tid & 63;
  const int w    = tid >> 6;      // wave 0..7: cols [16w,16w+16) of each gate
  const int lrow = lane & 15;
  const int lg   = lane >> 4;
  const int blk  = blockIdx.x;

  if (blk >= GROUPS) {
    // ======================= producer: Z = x@W + bias ======================
    const int pb = blk - GROUPS;
    s16x8 bfrW[4][2];
    float biasg[4];
#pragma unroll
    for (int n = 0; n < 4; ++n) {
      const int p = n * HS + w * 16 + lrow;
#pragma unroll
      for (int kt = 0; kt < 2; ++kt)
#pragma unroll
        for (int j = 0; j < 8; ++j)
          bfrW[n][kt][j] = (short)f2bf(W[(kt * 32 + lg * 8 + j) * NG + p]);
      biasg[n] = B[p];
    }

#pragma unroll 1
    for (int u = pb; u < NUNITS; u += PRODS) {
      const int c = u >> 5, g = u & 31;
      const float* xrow = X + ((long)(g * RPG + lrow) * T_STEPS) * IN_DIM + lg * 8;
#pragma unroll 1
      for (int tl = 0; tl < CHK; ++tl) {
        const int t = c * CHK + tl;
        const float* xp = xrow + (long)t * IN_DIM;
        const f32x4 x0 = *(const f32x4*)(xp);
        const f32x4 x1 = *(const f32x4*)(xp + 4);
        const f32x4 x2 = *(const f32x4*)(xp + 32);
        const f32x4 x3 = *(const f32x4*)(xp + 36);
        s16x8 a0, a1;
#pragma unroll
        for (int j = 0; j < 4; ++j) {
          a0[j] = (short)f2bf(x0[j]); a0[4 + j] = (short)f2bf(x1[j]);
          a1[j] = (short)f2bf(x2[j]); a1[4 + j] = (short)f2bf(x3[j]);
        }
        f32x4 ac[4];
#pragma unroll
        for (int n = 0; n < 4; ++n) {
          ac[n][0] = biasg[n]; ac[n][1] = biasg[n];
          ac[n][2] = biasg[n]; ac[n][3] = biasg[n];
        }
#pragma unroll
        for (int n = 0; n < 4; ++n)
          ac[n] = __builtin_amdgcn_mfma_f32_16x16x32_bf16(a0, bfrW[n][0], ac[n], 0, 0, 0);
#pragma unroll
        for (int n = 0; n < 4; ++n)
          ac[n] = __builtin_amdgcn_mfma_f32_16x16x32_bf16(a1, bfrW[n][1], ac[n], 0, 0, 0);
        // pack scan-native: shorts[r*4+n]; lane's 16 shorts are contiguous 32B
        s16x8 zl, zh;
#pragma unroll
        for (int n = 0; n < 4; ++n) {
          zl[n] = (short)f2bf(ac[n][0]); zl[4 + n] = (short)f2bf(ac[n][1]);
          zh[n] = (short)f2bf(ac[n][2]); zh[4 + n] = (short)f2bf(ac[n][3]);
        }
        unsigned short* dst = Zbuf + (((long)t * GROUPS + g) * NTHR + tid) * 16;
        *(s16x8*)dst       = zl;
        *(s16x8*)(dst + 8) = zh;
      }
      __threadfence();
      __syncthreads();
      if (tid == 0)
        __hip_atomic_store(&flags[u], 1, __ATOMIC_RELEASE, __HIP_MEMORY_SCOPE_AGENT);
    }
    return;
  }

  // ========================== scan: 16 rows/block ==========================
  const int g = blk;
  s16x8 bfrU[4][4];
#pragma unroll
  for (int n = 0; n < 4; ++n) {
    const int p = n * HS + w * 16 + lrow;
#pragma unroll
    for (int kt = 0; kt < 4; ++kt)
#pragma unroll
      for (int j = 0; j < 8; ++j)
        bfrU[n][kt][j] = (short)f2bf(U[(kt * 32 + lg * 8 + j) * NG + p]);
  }
  for (int i = tid; i < 2 * RPG * HSTR; i += NTHR) ((short*)Hb)[i] = 0;  // h(0)=0

  wait_flag(&flags[g]);                       // chunk 0 ready
  __syncthreads();

  const long zstride = (long)GROUPS * NTHR * 16;              // shorts per t
  const unsigned short* zbase = Zbuf + ((long)g * NTHR + tid) * 16;
  s16x8 za0 = *(const s16x8*)(zbase);
  s16x8 za1 = *(const s16x8*)(zbase + 8);
  s16x8 zb0 = *(const s16x8*)(zbase + zstride);
  s16x8 zb1 = *(const s16x8*)(zbase + zstride + 8);

  s16x8 afr[4];
  const s16x8 zer = {0, 0, 0, 0, 0, 0, 0, 0};
#pragma unroll
  for (int kt = 0; kt < 4; ++kt) afr[kt] = zer;
  float cr[4] = {0.f, 0.f, 0.f, 0.f};

  const int col = w * 16 + lrow;

  auto step = [&](int t, s16x8& z0, s16x8& z1) {
    f32x4 acc[4];
#pragma unroll
    for (int n = 0; n < 4; ++n) {
      acc[n][0] = bf2f((unsigned short)z0[n]);
      acc[n][1] = bf2f((unsigned short)z0[4 + n]);
      acc[n][2] = bf2f((unsigned short)z1[n]);
      acc[n][3] = bf2f((unsigned short)z1[4 + n]);
    }
    // prefetch Z(t+2) into this slot (2 steps ~ full HBM latency cover)
    {
      const int tn = (t + 2 < T_STEPS) ? t + 2 : T_STEPS - 1;
      const unsigned short* src = zbase + (long)tn * zstride;
      z0 = *(const s16x8*)src;
      z1 = *(const s16x8*)(src + 8);
    }

    __builtin_amdgcn_s_setprio(1);
#pragma unroll
    for (int kt = 0; kt < 4; ++kt)
      acc[0] = __builtin_amdgcn_mfma_f32_16x16x32_bf16(afr[kt], bfrU[0][kt], acc[0], 0, 0, 0);
#pragma unroll
    for (int kt = 0; kt < 4; ++kt)
      acc[2] = __builtin_amdgcn_mfma_f32_16x16x32_bf16(afr[kt], bfrU[2][kt], acc[2], 0, 0, 0);
#pragma unroll
    for (int kt = 0; kt < 4; ++kt)
      acc[1] = __builtin_amdgcn_mfma_f32_16x16x32_bf16(afr[kt], bfrU[1][kt], acc[1], 0, 0, 0);
#pragma unroll
    for (int kt = 0; kt < 4; ++kt)
      acc[3] = __builtin_amdgcn_mfma_f32_16x16x32_bf16(afr[kt], bfrU[3][kt], acc[3], 0, 0, 0);
    __builtin_amdgcn_s_setprio(0);

    // 4 full cell updates per lane: acc[n][r] = gate n at (row 4lg+r, col)
    float hv[4];
#pragma unroll
    for (int r = 0; r < 4; ++r) {
      const float iv = sigm(acc[0][r]);
      const float fv = sigm(acc[1][r]);
      const float gv = tanhfast(acc[2][r]);
      const float ov = sigm(acc[3][r]);
      cr[r] = fv * cr[r] + iv * gv;
      hv[r] = ov * tanhfast(cr[r]);
    }

    if (t < T_STEPS - 1) {
      short* hb = &Hb[(t + 1) & 1][0];
#pragma unroll
      for (int r = 0; r < 4; ++r)
        hb[(4 * lg + r) * HSTR + col] = (short)f2bf(hv[r]);
    } else {
#pragma unroll
      for (int r = 0; r < 4; ++r) {
        const int row = g * RPG + 4 * lg + r;
        OUT[512 + row * HS + col]   = hv[r];     // h_t
        OUT[66048 + row * HS + col] = cr[r];     // c_t
        Ys[(4 * lg + r) * HS + col] = LW[col] * hv[r];
      }
    }

    // mid-chunk: acquire next chunk's flag (producers run ~7 chunks ahead)
    if ((t & 31) == 16 && ((t >> 5) + 1) < NCHK)
      wait_flag(&flags[((t >> 5) + 1) * GROUPS + g]);

    __syncthreads();

    if (t < T_STEPS - 1) {
      const short* hb = &Hb[(t + 1) & 1][lrow * HSTR];
      afr[0] = *(const s16x8*)&hb[lg * 8];
      afr[1] = *(const s16x8*)&hb[32 + lg * 8];
      afr[2] = *(const s16x8*)&hb[64 + lg * 8];
      afr[3] = *(const s16x8*)&hb[96 + lg * 8];
    }
  };

#pragma unroll 1
  for (int t = 0; t < T_STEPS; t += 2) {
    step(t, za0, za1);
    step(t + 1, zb0, zb1);
  }

  __syncthreads();
  // y = h @ linear_w.T + b : wave w reduces local rows 2w, 2w+1
#pragma unroll
  for (int rr = 0; rr < 2; ++rr) {
    const int row = w * 2 + rr;
    float v = Ys[row * HS + lane] + Ys[row * HS + 64 + lane];
#pragma unroll
    for (int off = 32; off > 0; off >>= 1) v += __shfl_down(v, off);
    if (lane == 0) OUT[g * RPG + row] = v + LB[0];
  }
}

// ---------------------------------------------------------------------------
// Fallback (ws too small): R5 fused kernel, 256 blocks x 2 rows.
// ---------------------------------------------------------------------------
#define ROWS 2
#define CH 64
#define NCH (T_STEPS / CH)

__global__ __launch_bounds__(NTHR, 1)
void lstm_fused(const float* __restrict__ X, const float* __restrict__ W,
                const float* __restrict__ U, const float* __restrict__ B,
                const float* __restrict__ LW, const float* __restrict__ LB,
                float* __restrict__ OUT) {
  __shared__ __align__(16) short Zc[CH * 128 * 8];
  __shared__ __align__(16) short Hb[2][ROWS * 144];
  __shared__ float Ys[256];
  __shared__ float Ps[8];

  const int tid  = threadIdx.x;
  const int lane = tid & 63;
  const int w    = tid >> 6;
  const int blk  = blockIdx.x;
  const int lrow = lane & 15;
  const int lg   = lane >> 4;
  const int col8 = (w * 16 + lrow) * 8;

  s16x8 bfrU[4][4];
  s16x8 bfrW[4][2];
  float biasg[4];
#pragma unroll
  for (int n = 0; n < 4; ++n) {
    const int p = n * HS + w * 16 + lrow;
#pragma unroll
    for (int kt = 0; kt < 4; ++kt)
#pragma unroll
      for (int j = 0; j < 8; ++j)
        bfrU[n][kt][j] = (short)f2bf(U[(kt * 32 + (lg << 3) + j) * NG + p]);
#pragma unroll
    for (int kt = 0; kt < 2; ++kt)
#pragma unroll
      for (int j = 0; j < 8; ++j)
        bfrW[n][kt][j] = (short)f2bf(W[(kt * 32 + (lg << 3) + j) * NG + p]);
    biasg[n] = B[p];
  }

  const float* xbA = X + ((long)(blk * ROWS + (lrow & 1)) * T_STEPS + (lrow >> 1)) * IN_DIM + (lg << 3);
  f32x4 qp0 = *(const f32x4*)(xbA);
  f32x4 qp1 = *(const f32x4*)(xbA + 4);
  f32x4 qp2 = *(const f32x4*)(xbA + 32);
  f32x4 qp3 = *(const f32x4*)(xbA + 36);

  s16x8 afr[4];
  const s16x8 zer = {0, 0, 0, 0, 0, 0, 0, 0};
#pragma unroll
  for (int kt = 0; kt < 4; ++kt) afr[kt] = zer;
  float creg = 0.f, hreg = 0.f;

#pragma unroll 1
  for (int c = 0; c < NCH; ++c) {
    {
      const float* xc = xbA + (long)c * CH * IN_DIM;
      f32x4 q0 = qp0, q1 = qp1, q2 = qp2, q3 = qp3;
#pragma unroll
      for (int mt = 0; mt < 8; ++mt) {
        f32x4 n0, n1, n2, n3;
        if (mt < 7) {
          const float* p = xc + (mt + 1) * 8 * IN_DIM;
          n0 = *(const f32x4*)(p);      n1 = *(const f32x4*)(p + 4);
          n2 = *(const f32x4*)(p + 32); n3 = *(const f32x4*)(p + 36);
        }
        s16x8 a0, a1;
#pragma unroll
        for (int j = 0; j < 4; ++j) {
          a0[j] = (short)f2bf(q0[j]); a0[4 + j] = (short)f2bf(q1[j]);
          a1[j] = (short)f2bf(q2[j]); a1[4 + j] = (short)f2bf(q3[j]);
        }
        f32x4 ac[4];
#pragma unroll
        for (int n = 0; n < 4; ++n) {
          ac[n][0] = biasg[n]; ac[n][1] = biasg[n];
          ac[n][2] = biasg[n]; ac[n][3] = biasg[n];
        }
#pragma unroll
        for (int n = 0; n < 4; ++n)
          ac[n] = __builtin_amdgcn_mfma_f32_16x16x32_bf16(a0, bfrW[n][0], ac[n], 0, 0, 0);
#pragma unroll
        for (int n = 0; n < 4; ++n)
          ac[n] = __builtin_amdgcn_mfma_f32_16x16x32_bf16(a1, bfrW[n][1], ac[n], 0, 0, 0);
        s16x8 z0, z1;
#pragma unroll
        for (int n = 0; n < 4; ++n) {
          z0[n] = (short)f2bf(ac[n][0]); z0[4 + n] = (short)f2bf(ac[n][1]);
          z1[n] = (short)f2bf(ac[n][2]); z1[4 + n] = (short)f2bf(ac[n][3]);
        }
        const int tl0 = mt * 8 + 2 * lg;
        *(s16x8*)&Zc[tl0 * 1024 + col8]       = z0;
        *(s16x8*)&Zc[(tl0 + 1) * 1024 + col8] = z1;
        q0 = n0; q1 = n1; q2 = n2; q3 = n3;
      }
      const float* pn = xbA + (long)((c + 1 < NCH) ? c + 1 : c) * CH * IN_DIM;
      qp0 = *(const f32x4*)(pn);      qp1 = *(const f32x4*)(pn + 4);
      qp2 = *(const f32x4*)(pn + 32); qp3 = *(const f32x4*)(pn + 36);
    }
    __syncthreads();

#pragma unroll 1
    for (int tl = 0; tl < CH; ++tl) {
      const int t = (c << 6) + tl;
      const s16x8 zc = *(const s16x8*)&Zc[tl * 1024 + col8];
      f32x4 acc[4];
#pragma unroll
      for (int n = 0; n < 4; ++n) {
        acc[n][0] = bf2f((unsigned short)zc[n]);
        acc[n][1] = bf2f((unsigned short)zc[4 + n]);
        acc[n][2] = 0.f; acc[n][3] = 0.f;
      }
      __builtin_amdgcn_s_setprio(1);
#pragma unroll
      for (int kt = 0; kt < 4; ++kt)
        acc[0] = __builtin_amdgcn_mfma_f32_16x16x32_bf16(afr[kt], bfrU[0][kt], acc[0], 0, 0, 0);
#pragma unroll
      for (int kt = 0; kt < 4; ++kt)
        acc[2] = __builtin_amdgcn_mfma_f32_16x16x32_bf16(afr[kt], bfrU[2][kt], acc[2], 0, 0, 0);
#pragma unroll
      for (int kt = 0; kt < 4; ++kt)
        acc[1] = __builtin_amdgcn_mfma_f32_16x16x32_bf16(afr[kt], bfrU[1][kt], acc[1], 0, 0, 0);
#pragma unroll
      for (int kt = 0; kt < 4; ++kt)
        acc[3] = __builtin_amdgcn_mfma_f32_16x16x32_bf16(afr[kt], bfrU[3][kt], acc[3], 0, 0, 0);
      __builtin_amdgcn_s_setprio(0);

      const float s0 = __int_as_float(
          __builtin_amdgcn_ds_swizzle(__float_as_int(acc[0][1]), 0x401F));
      const float s2 = __int_as_float(
          __builtin_amdgcn_ds_swizzle(__float_as_int(acc[2][1]), 0x401F));
      const float v0 = (lane & 16) ? s0 : acc[0][0];
      const float v2 = (lane & 16) ? s2 : acc[2][0];
      const float iv = sigm(v0), gv = tanhfast(v2);
      const float pg = iv * gv;
      const float s1 = __int_as_float(
          __builtin_amdgcn_ds_swizzle(__float_as_int(acc[1][1]), 0x401F));
      const float s3 = __int_as_float(
          __builtin_amdgcn_ds_swizzle(__float_as_int(acc[3][1]), 0x401F));
      const float v1 = (lane & 16) ? s1 : acc[1][0];
      const float v3 = (lane & 16) ? s3 : acc[3][0];
      const float fv = sigm(v1), ov = sigm(v3);
      creg = fv * creg + pg;
      hreg = ov * tanhfast(creg);

      if (lane < 32) {
        const int colc = w * 16 + lrow;
        const int r    = lg & 1;
        if (t < T_STEPS - 1) {
          Hb[(t + 1) & 1][r * 144 + colc] = (short)f2bf(hreg);
        } else {
          const int row = blk * ROWS + r;
          OUT[512 + row * HS + colc]   = hreg;
          OUT[66048 + row * HS + colc] = creg;
          Ys[r * HS + colc] = LW[colc] * hreg;
        }
      }
      __syncthreads();

      if (t < T_STEPS - 1 && lrow < ROWS) {
        const short* hb = &Hb[(t + 1) & 1][lrow * 144];
        afr[0] = *(const s16x8*)&hb[(lg << 3)];
        afr[1] = *(const s16x8*)&hb[32 + (lg << 3)];
        afr[2] = *(const s16x8*)&hb[64 + (lg << 3)];
        afr[3] = *(const s16x8*)&hb[96 + (lg << 3)];
      }
    }
  }

  if (tid < 8) {
    const int r = tid >> 2, seg = tid & 3;
    float s = 0.f;
#pragma unroll 8
    for (int j = 0; j < 32; ++j) s += Ys[r * 128 + seg * 32 + j];
    Ps[tid] = s;
  }
  __syncthreads();
  if (tid < ROWS) {
    OUT[blk * ROWS + tid] = LB[0] + Ps[tid * 4] + Ps[tid * 4 + 1]
                                  + Ps[tid * 4 + 2] + Ps[tid * 4 + 3];
  }
}

extern "C" void kernel_launch(void* const* d_in, const int* in_sizes, int n_in,
                              void* d_out, int out_size, void* d_ws, size_t ws_size,
                              hipStream_t stream) {
  const float* X  = (const float*)d_in[0];
  const float* W  = (const float*)d_in[1];
  const float* U  = (const float*)d_in[2];
  const float* B  = (const float*)d_in[3];
  const float* LW = (const float*)d_in[4];
  const float* LB = (const float*)d_in[5];
  const size_t ZBYTES = (size_t)T_STEPS * GROUPS * NTHR * 16 * 2;  // 1 GiB
  const size_t FBYTES = (size_t)NUNITS * 4;
  if (ws_size >= ZBYTES + FBYTES) {
    unsigned short* Zbuf = (unsigned short*)d_ws;
    int* flags = (int*)((char*)d_ws + ZBYTES);
    hipMemsetAsync(flags, 0, FBYTES, stream);
    lstm_mega<<<dim3(GROUPS + PRODS), dim3(NTHR), 0, stream>>>(
        X, W, U, B, LW, LB, (float*)d_out, Zbuf, flags);
  } else {
    lstm_fused<<<dim3(256), dim3(NTHR), 0, stream>>>(X, W, U, B, LW, LB, (float*)d_out);
  }
}